// Round 4
// baseline (391.213 us; speedup 1.0000x reference)
//
#include <hip/hip_runtime.h>

#define NGRID 8192
#define NLAYER 24
#define NPERIODS 50
#define NOBS 4096
#define NC 200
#define PP 64            // r_pad row padded to 64 (zero for p>=50)
#define NSPLIT 16        // g-splits across blockIdx.y in K2
#define GC (NGRID / NSPLIT)   // 512 g per block
#define KG 32            // g subtile staged in LDS per block
#define ASTR 36          // LDS stride: 0 bank conflicts measured in R1
#define NPW 13           // periods per wave (4 waves cover 52 >= 50; pad reads are 0)
#define NBINS 1024
#define OTILE 64
#define VREF 3.0f

// ---------------- K1: r_pad[g][p] = 1/(0.92 * sum_l w[p][l]*Vs[g][l]); block 0 zeroes bins ----------------
__global__ __launch_bounds__(256) void k1_rpad(const float* __restrict__ Vs,
                                               const float* __restrict__ thick,
                                               const float* __restrict__ periods,
                                               float* __restrict__ r_pad,
                                               float* __restrict__ bins) {
    __shared__ float w_sh[NLAYER][NPERIODS];   // transposed: reads are conflict-free
    __shared__ float z_sh[NLAYER];
    int tid = threadIdx.x;
    if (blockIdx.x == 0) {
        for (int i = tid; i < NBINS; i += 256) bins[i] = 0.f;
    }
    if (tid < NLAYER) {
        float c = 0.f;
        for (int i = 0; i <= tid; ++i) c += thick[i];
        z_sh[tid] = c - 0.5f * thick[tid];
    }
    __syncthreads();
    if (tid < NPERIODS) {
        float ds = (VREF / 3.0f) * periods[tid];
        float tmp[NLAYER];
        float s = 0.f;
        #pragma unroll
        for (int l = 0; l < NLAYER; ++l) {
            float v = expf(-z_sh[l] / ds) * thick[l];
            tmp[l] = v; s += v;
        }
        float inv = 1.f / s;
        #pragma unroll
        for (int l = 0; l < NLAYER; ++l) w_sh[l][tid] = tmp[l] * inv;
    }
    __syncthreads();
    int idx = blockIdx.x * 256 + tid;          // idx = g*64 + p  (lanes share g -> broadcast Vs)
    int g = idx >> 6, p = idx & 63;
    float r = 0.f;
    if (p < NPERIODS) {
        const float4* vp = (const float4*)(Vs + (size_t)g * NLAYER);
        float s = 0.f;
        #pragma unroll
        for (int q = 0; q < NLAYER / 4; ++q) {
            float4 t = vp[q];
            s = fmaf(w_sh[4*q+0][p], t.x, s);
            s = fmaf(w_sh[4*q+1][p], t.y, s);
            s = fmaf(w_sh[4*q+2][p], t.z, s);
            s = fmaf(w_sh[4*q+3][p], t.w, s);
        }
        r = 1.0f / (0.92f * s);
    }
    r_pad[idx] = r;                            // fully coalesced, zero-padded p>=50
}

// ---------------- K2: partial_t[s][p][o] = sum_{g in split s} A[o][g]*r[g][p] ----------------
// lane <-> obs; the 4 waves of a block SPLIT the 50 periods (13 each) and SHARE
// one block-level A tile. acc[13]/lane => ~45 VGPR, spill-proof (R2/R3 lesson:
// acc[50] spills whenever the scheduler hoists staging loads). Each A element
// still amortized over 50 p block-wide. 1024 blocks = 4/CU = 32 waves/CU.
__global__ __launch_bounds__(256) void k2_gemm(const float* __restrict__ A,
                                               const float* __restrict__ r_pad,
                                               float* __restrict__ partial_t) {
    __shared__ float Aw[OTILE * ASTR];                     // 9216 B
    int tid  = threadIdx.x;
    int lane = tid & 63;
    int wv   = __builtin_amdgcn_readfirstlane(tid >> 6);   // uniform -> s_load of r
    int o_base = blockIdx.x * OTILE;
    int split  = blockIdx.y;
    int pbase  = wv * NPW;                                 // 0,13,26,39

    float acc[NPW];
    #pragma unroll
    for (int p = 0; p < NPW; ++p) acc[p] = 0.f;

    int g_blk = split * GC;

    #pragma unroll 1
    for (int kt = 0; kt < GC / KG; ++kt) {                 // 16 subtiles of 32 g
        int g0 = g_blk + kt * KG;
        __syncthreads();                                   // previous tile fully consumed
        // stage 64 obs x 32 g: 2 float4 per thread; 8 threads cover 128B per obs-row
        #pragma unroll
        for (int s = 0; s < 2; ++s) {
            int f   = s * 256 + tid;
            int row = f >> 3;
            int c4  = (f & 7) * 4;
            float4 t = *(const float4*)(A + (size_t)(o_base + row) * NGRID + g0 + c4);
            *(float4*)(Aw + row * ASTR + c4) = t;
        }
        __syncthreads();
        #pragma unroll 1
        for (int gg = 0; gg < KG; gg += 4) {
            float4 a4 = *(const float4*)(Aw + lane * ASTR + gg);
            const float* rr = r_pad + (size_t)(g0 + gg) * PP + pbase;  // uniform -> s_load
            #pragma unroll
            for (int j = 0; j < 4; ++j) {
                float aj = (j == 0) ? a4.x : (j == 1) ? a4.y : (j == 2) ? a4.z : a4.w;
                #pragma unroll
                for (int p = 0; p < NPW; ++p)
                    acc[p] = fmaf(aj, rr[j * PP + p], acc[p]);   // p>=50 reads pad=0
            }
        }
    }

    // epilogue: each wave owns its p's -> direct coalesced stores, no LDS, no reduce
    float* outp = partial_t + (size_t)split * (NPERIODS * NOBS);
    #pragma unroll
    for (int p = 0; p < NPW; ++p) {
        int pp = pbase + p;
        if (pp < NPERIODS)
            outp[(size_t)pp * NOBS + o_base + lane] = acc[p];
    }
}

// ---------------- K2b: cpred_t[p][o] = 1 / sum_s partial_t[s][p][o]  (fully coalesced) ----------------
__global__ __launch_bounds__(256) void k2b_reduce(const float* __restrict__ partial_t,
                                                  float* __restrict__ cpred_t) {
    int idx = blockIdx.x * 256 + threadIdx.x;              // < 50*4096
    float s = 0.f;
    #pragma unroll
    for (int sp = 0; sp < NSPLIT; ++sp)
        s += partial_t[(size_t)sp * (NPERIODS * NOBS) + idx];
    cpred_t[idx] = 1.0f / s;
}

// ---------------- K3: block per obs; ballot searchsorted, shuffle interp, 2 rows in flight ----------------
__global__ __launch_bounds__(256) void k3_main(const float* __restrict__ energy,
                                               const float* __restrict__ c_axis,
                                               const float* __restrict__ cpred_t,
                                               float* __restrict__ bins) {
    __shared__ float csh[NC];
    __shared__ float red[4];
    int tid  = threadIdx.x;
    int lane = tid & 63;
    int wv   = tid >> 6;
    int o    = blockIdx.x;

    if (tid < NC) csh[tid] = c_axis[(size_t)o * NC + tid];
    __syncthreads();

    bool act = lane < NC / 4;                  // 50 active lanes
    float4 ca = act ? *(const float4*)(csh + 4 * lane) : make_float4(9e30f, 9e30f, 9e30f, 9e30f);
    const float* ebase = energy + (size_t)o * NPERIODS * NC;
    float local = 0.f;

    for (int p0 = wv; p0 < NPERIODS; p0 += 8) {
        int p1 = p0 + 4;
        bool has1 = p1 < NPERIODS;
        int p1c = has1 ? p1 : p0;
        float cpA = cpred_t[(size_t)p0 * NOBS + o];        // wave-uniform broadcast
        float cpB = cpred_t[(size_t)p1c * NOBS + o];
        const float* erA = ebase + (size_t)p0 * NC;
        const float* erB = ebase + (size_t)p1c * NC;
        float4 eA = act ? *(const float4*)(erA + 4 * lane) : make_float4(-1e30f, -1e30f, -1e30f, -1e30f);
        float4 eB = act ? *(const float4*)(erB + 4 * lane) : make_float4(-1e30f, -1e30f, -1e30f, -1e30f);

        // searchsorted 'left' = count(c_axis < cp) via ballot+popcount (scalar pipe)
        int cntA = __popcll(__ballot(ca.x < cpA)) + __popcll(__ballot(ca.y < cpA))
                 + __popcll(__ballot(ca.z < cpA)) + __popcll(__ballot(ca.w < cpA));
        int cntB = __popcll(__ballot(ca.x < cpB)) + __popcll(__ballot(ca.y < cpB))
                 + __popcll(__ballot(ca.z < cpB)) + __popcll(__ballot(ca.w < cpB));

        // row max: two independent butterfly chains interleaved
        float mA = fmaxf(fmaxf(eA.x, eA.y), fmaxf(eA.z, eA.w));
        float mB = fmaxf(fmaxf(eB.x, eB.y), fmaxf(eB.z, eB.w));
        #pragma unroll
        for (int m = 32; m; m >>= 1) {
            mA = fmaxf(mA, __shfl_xor(mA, m, 64));
            mB = fmaxf(mB, __shfl_xor(mB, m, 64));
        }

        int iA = cntA < 1 ? 1 : (cntA > NC - 1 ? NC - 1 : cntA);
        int iB = cntB < 1 ? 1 : (cntB > NC - 1 ? NC - 1 : cntB);

        // e0/e1 from registers by shuffle (idx is wave-uniform)
        int a0 = iA - 1, a1 = iA, b0 = iB - 1, b1 = iB;
        float sA0 = ((a0 & 3) == 0) ? eA.x : ((a0 & 3) == 1) ? eA.y : ((a0 & 3) == 2) ? eA.z : eA.w;
        float sA1 = ((a1 & 3) == 0) ? eA.x : ((a1 & 3) == 1) ? eA.y : ((a1 & 3) == 2) ? eA.z : eA.w;
        float sB0 = ((b0 & 3) == 0) ? eB.x : ((b0 & 3) == 1) ? eB.y : ((b0 & 3) == 2) ? eB.z : eB.w;
        float sB1 = ((b1 & 3) == 0) ? eB.x : ((b1 & 3) == 1) ? eB.y : ((b1 & 3) == 2) ? eB.z : eB.w;
        float e0A = __shfl(sA0, a0 >> 2, 64), e1A = __shfl(sA1, a1 >> 2, 64);
        float e0B = __shfl(sB0, b0 >> 2, 64), e1B = __shfl(sB1, b1 >> 2, 64);

        float c0A = csh[a0], c1A = csh[a1];
        float c0B = csh[b0], c1B = csh[b1];
        float wA = (cpA - c0A) / (c1A - c0A + 1e-12f);
        float wB = (cpB - c0B) / (c1B - c0B + 1e-12f);
        float eiA = fmaf(wA, e1A - e0A, e0A);
        float eiB = fmaf(wB, e1B - e0B, e0B);
        local += mA - eiA;
        local += has1 ? (mB - eiB) : 0.f;
    }
    if (lane == 0) red[wv] = local;
    __syncthreads();
    if (tid == 0)
        atomicAdd(&bins[blockIdx.x & (NBINS - 1)], red[0] + red[1] + red[2] + red[3]);
}

// ---------------- K4: final reduce of bins -> out ----------------
__global__ __launch_bounds__(256) void k4_final(const float* __restrict__ bins,
                                                float* __restrict__ out) {
    __shared__ float red[4];
    int tid = threadIdx.x;
    float s = 0.f;
    for (int i = tid; i < NBINS; i += 256) s += bins[i];
    #pragma unroll
    for (int m = 32; m; m >>= 1) s += __shfl_xor(s, m, 64);
    int lane = tid & 63, wv = tid >> 6;
    if (lane == 0) red[wv] = s;
    __syncthreads();
    if (tid == 0) out[0] = -(red[0] + red[1] + red[2] + red[3]);  // / SIGMA^2 == 1
}

extern "C" void kernel_launch(void* const* d_in, const int* in_sizes, int n_in,
                              void* d_out, int out_size, void* d_ws, size_t ws_size,
                              hipStream_t stream) {
    const float* Vs      = (const float*)d_in[0];
    const float* A       = (const float*)d_in[1];
    const float* energy  = (const float*)d_in[2];
    const float* c_axis  = (const float*)d_in[3];
    const float* thick   = (const float*)d_in[4];
    const float* periods = (const float*)d_in[5];
    float* out = (float*)d_out;

    float* ws        = (float*)d_ws;
    float* r_pad     = ws;                                          // 2 MB
    float* partial_t = r_pad + (size_t)NGRID * PP;                  // 16*50*4096*4 = 13.1 MB
    float* cpred_t   = partial_t + (size_t)NSPLIT * NPERIODS * NOBS;// 800 KB
    float* bins      = cpred_t + (size_t)NPERIODS * NOBS;           // 4 KB

    hipLaunchKernelGGL(k1_rpad, dim3((NGRID * 64) / 256), dim3(256), 0, stream,
                       Vs, thick, periods, r_pad, bins);
    hipLaunchKernelGGL(k2_gemm, dim3(NOBS / OTILE, NSPLIT), dim3(256), 0, stream,
                       A, r_pad, partial_t);
    hipLaunchKernelGGL(k2b_reduce, dim3((NPERIODS * NOBS) / 256), dim3(256), 0, stream,
                       partial_t, cpred_t);
    hipLaunchKernelGGL(k3_main, dim3(NOBS), dim3(256), 0, stream,
                       energy, c_axis, cpred_t, bins);
    hipLaunchKernelGGL(k4_final, dim3(1), dim3(256), 0, stream, bins, out);
}